// Round 2
// baseline (422.082 us; speedup 1.0000x reference)
//
#include <hip/hip_runtime.h>
#include <hip/hip_bf16.h>
#include <stdint.h>

#define N_NODES 100000
#define HEADS 4
#define NE 1600000
#define NEG_SLOPE 0.2f
#define NSTRIP 6250   /* N_NODES/16 */

typedef __attribute__((ext_vector_type(8))) short bf16x8;
typedef __attribute__((ext_vector_type(4))) float f32x4;
typedef __attribute__((ext_vector_type(2))) float f32x2;

__device__ __forceinline__ short f2bf(float f) {
    __hip_bfloat16 b = __float2bfloat16(f);
    short s; __builtin_memcpy(&s, &b, 2); return s;
}

// ---------------- K0: vv[k][0..3]=W·a_src (per head), vv[k][4..7]=W·a_dst ----------
__global__ __launch_bounds__(128) void k_prep(const float* __restrict__ W,
                                              const float* __restrict__ a_src,
                                              const float* __restrict__ a_dst,
                                              float* __restrict__ vv) {
    int k = threadIdx.x;              // 0..127
    const float* wrow = W + k * 128;
    #pragma unroll
    for (int hd = 0; hd < 4; ++hd) {
        float va = 0.f, vd = 0.f;
        #pragma unroll
        for (int d = 0; d < 32; ++d) {
            float w = wrow[hd * 32 + d];
            va += w * a_src[hd * 32 + d];
            vd += w * a_dst[hd * 32 + d];
        }
        vv[k * 8 + hd]     = va;
        vv[k * 8 + 4 + hd] = vd;
    }
}

// ---------------- K1: h=bf16(x@W) via MFMA + exact fp32 scores sv = x@vv ------------
__global__ __launch_bounds__(256) void k_gemm(const float* __restrict__ x,
                                              const float* __restrict__ W,
                                              const float* __restrict__ vv,
                                              __hip_bfloat16* __restrict__ h,
                                              float* __restrict__ sv) {
    __shared__ short wt[16384];   // swizzled Wt bf16 (32KB); reused for h transpose
    __shared__ float vvl[1024];
    const int t = threadIdx.x;

    // stage W (fp32) -> bf16 transposed + XOR swizzled
    #pragma unroll 4
    for (int i = 0; i < 64; ++i) {
        int idx = t + i * 256;                 // 16384 elems of W
        int k = idx >> 7, c = idx & 127;
        int byte = ((c << 8) + (k << 1)) ^ ((c & 7) << 4);
        *(short*)((char*)wt + byte) = f2bf(W[idx]);
    }
    *(f32x4*)(vvl + t * 4) = *(const f32x4*)(vv + t * 4);
    __syncthreads();

    const int wid = t >> 6, lane = t & 63;
    const int strip = blockIdx.x * 4 + wid;
    const bool active = strip < NSTRIP;
    const int r0 = strip * 16;
    const int lr = lane & 15, lg = lane >> 4;

    f32x4 acc[8];
    #pragma unroll
    for (int ct = 0; ct < 8; ++ct) acc[ct] = (f32x4){0.f, 0.f, 0.f, 0.f};
    float part[8];
    #pragma unroll
    for (int i = 0; i < 8; ++i) part[i] = 0.f;

    if (active) {
        bf16x8 a[4];
        #pragma unroll
        for (int kk = 0; kk < 4; ++kk) {
            const float* xp = x + (size_t)(r0 + lr) * 128 + kk * 32 + lg * 8;
            f32x4 x0 = *(const f32x4*)xp;
            f32x4 x1 = *(const f32x4*)(xp + 4);
            int kbase = kk * 32 + lg * 8;
            #pragma unroll
            for (int j = 0; j < 4; ++j) {
                a[kk][j]     = f2bf(x0[j]);
                a[kk][4 + j] = f2bf(x1[j]);
                f32x4 v0 = *(const f32x4*)(vvl + (kbase + j) * 8);
                f32x4 v1 = *(const f32x4*)(vvl + (kbase + j) * 8 + 4);
                f32x4 w0 = *(const f32x4*)(vvl + (kbase + 4 + j) * 8);
                f32x4 w1 = *(const f32x4*)(vvl + (kbase + 4 + j) * 8 + 4);
                #pragma unroll
                for (int i = 0; i < 4; ++i) {
                    part[i]     += x0[j] * v0[i] + x1[j] * w0[i];
                    part[4 + i] += x0[j] * v1[i] + x1[j] * w1[i];
                }
            }
        }
        #pragma unroll
        for (int ct = 0; ct < 8; ++ct) {
            int c = ct * 16 + lr;
            #pragma unroll
            for (int kk = 0; kk < 4; ++kk) {
                int byte = ((c << 8) + ((kk * 32 + lg * 8) << 1)) ^ ((c & 7) << 4);
                bf16x8 b = *(const bf16x8*)((char*)wt + byte);
                acc[ct] = __builtin_amdgcn_mfma_f32_16x16x32_bf16(a[kk], b, acc[ct], 0, 0, 0);
            }
        }
    }
    // butterfly-reduce score partials across the 4 lane-groups sharing a row
    #pragma unroll
    for (int i = 0; i < 8; ++i) {
        part[i] += __shfl_xor(part[i], 16);
        part[i] += __shfl_xor(part[i], 32);
    }
    if (active && lg == 0) {
        f32x4 s0, s1;
        #pragma unroll
        for (int j = 0; j < 4; ++j) { s0[j] = part[j]; s1[j] = part[4 + j]; }
        *(f32x4*)(sv + (size_t)(r0 + lr) * 8)     = s0;
        *(f32x4*)(sv + (size_t)(r0 + lr) * 8 + 4) = s1;
    }
    __syncthreads();
    // write h tile (bf16) into LDS [64 rows][128 ch], then coalesced store
    if (active) {
        #pragma unroll
        for (int ct = 0; ct < 8; ++ct) {
            #pragma unroll
            for (int j = 0; j < 4; ++j) {
                int row = wid * 16 + lg * 4 + j;
                wt[row * 128 + ct * 16 + lr] = f2bf(acc[ct][j]);
            }
        }
    }
    __syncthreads();
    const int R0 = blockIdx.x * 64;
    #pragma unroll
    for (int cch = 0; cch < 4; ++cch) {
        int sidx = (cch * 256 + t) * 8;        // short index into 16384
        int grow = R0 + (sidx >> 7);
        if (grow < N_NODES)
            *(bf16x8*)((short*)h + (size_t)grow * 128 + (sidx & 127)) = *(const bf16x8*)(wt + sidx);
    }
}

// ---------------- K3: degree histogram ---------------------------------------------
__global__ __launch_bounds__(256) void k_deg(const int* __restrict__ ei, int* __restrict__ deg) {
    int e = blockIdx.x * 256 + threadIdx.x;
    if (e >= NE) return;
    atomicAdd(&deg[ei[NE + e]], 1);
}

// ---------------- K4: exclusive scan (single block) ---------------------------------
__global__ __launch_bounds__(1024) void k_scan(const int* __restrict__ deg, int* __restrict__ offs) {
    __shared__ int wsum[16];
    int t = threadIdx.x;
    int lane = t & 63, wid = t >> 6;
    int running = 0;
    for (int base = 0; base < N_NODES; base += 4096) {
        int i0 = base + t * 4;
        int d0 = (i0 + 0 < N_NODES) ? deg[i0 + 0] : 0;
        int d1 = (i0 + 1 < N_NODES) ? deg[i0 + 1] : 0;
        int d2 = (i0 + 2 < N_NODES) ? deg[i0 + 2] : 0;
        int d3 = (i0 + 3 < N_NODES) ? deg[i0 + 3] : 0;
        int tsum = d0 + d1 + d2 + d3;
        int incl = tsum;
        #pragma unroll
        for (int off = 1; off < 64; off <<= 1) {
            int y = __shfl_up(incl, off);
            if (lane >= off) incl += y;
        }
        if (lane == 63) wsum[wid] = incl;
        __syncthreads();
        int wpre = 0, ctot = 0;
        #pragma unroll
        for (int w = 0; w < 16; ++w) {
            int v = wsum[w];
            if (w < wid) wpre += v;
            ctot += v;
        }
        int excl = running + wpre + (incl - tsum);
        if (i0 + 0 < N_NODES) offs[i0 + 0] = excl;
        if (i0 + 1 < N_NODES) offs[i0 + 1] = excl + d0;
        if (i0 + 2 < N_NODES) offs[i0 + 2] = excl + d0 + d1;
        if (i0 + 3 < N_NODES) offs[i0 + 3] = excl + d0 + d1 + d2;
        running += ctot;
        __syncthreads();
    }
    if (t == 0) offs[N_NODES] = running;
}

// ---------------- K5: scatter edges into CSR buckets --------------------------------
__global__ __launch_bounds__(256) void k_scatter(const int* __restrict__ ei,
                                                 const int* __restrict__ offs,
                                                 int* __restrict__ cursor,
                                                 int* __restrict__ srclist) {
    int e = blockIdx.x * 256 + threadIdx.x;
    if (e >= NE) return;
    int s = ei[e], d = ei[NE + e];
    int pos = atomicAdd(&cursor[d], 1);
    srclist[offs[d] + pos] = s;
}

// ---------------- K6: per-dst aggregate (one wave per node) -------------------------
__global__ __launch_bounds__(256) void k_aggregate(const __hip_bfloat16* __restrict__ h,
                                                   const float* __restrict__ sv,
                                                   const int* __restrict__ offs,
                                                   const int* __restrict__ srclist,
                                                   float* __restrict__ out) {
    int gw = (blockIdx.x * 256 + threadIdx.x) >> 6;
    if (gw >= N_NODES) return;
    int n = gw;
    int lane = threadIdx.x & 63;
    int head = lane >> 4;             // channels 2*lane,2*lane+1 belong to head lane>>4
    float sd = sv[(size_t)n * 8 + 4 + head];
    int b = offs[n], e = offs[n + 1];
    float acc0 = 0.f, acc1 = 0.f, wsum = 0.f;
    const uint32_t* hp = (const uint32_t*)h;
    for (int j = b; j < e; ++j) {
        int src = srclist[j];
        float ew = sv[(size_t)src * 8 + head] + sd;
        ew = ew > 0.f ? ew : NEG_SLOPE * ew;
        float w = __expf(ew);
        uint32_t p = hp[(size_t)src * 64 + lane];
        union { uint32_t i; float f; } u0, u1;
        u0.i = p << 16;
        u1.i = p & 0xffff0000u;
        acc0 += w * u0.f;
        acc1 += w * u1.f;
        wsum += w;
    }
    float inv = 1.f / (wsum + 1e-9f);
    f32x2 o = {acc0 * inv, acc1 * inv};
    *(f32x2*)(out + (size_t)n * 128 + lane * 2) = o;
}

extern "C" void kernel_launch(void* const* d_in, const int* in_sizes, int n_in,
                              void* d_out, int out_size, void* d_ws, size_t ws_size,
                              hipStream_t stream) {
    const float* x     = (const float*)d_in[0];
    const int*   ei    = (const int*)d_in[1];
    const float* W     = (const float*)d_in[2];
    const float* a_src = (const float*)d_in[3];
    const float* a_dst = (const float*)d_in[4];
    float* out = (float*)d_out;

    char* ws = (char*)d_ws;
    size_t off = 0;
    auto alloc = [&](size_t bytes) {
        char* p = ws + off;
        off += (bytes + 255) & ~(size_t)255;
        return p;
    };
    __hip_bfloat16* h = (__hip_bfloat16*)alloc((size_t)N_NODES * 128 * 2);
    float* sv         = (float*)alloc((size_t)N_NODES * 8 * 4);
    float* vv         = (float*)alloc(1024 * 4);
    int* deg          = (int*)alloc((size_t)N_NODES * 4);
    int* cursor       = (int*)alloc((size_t)N_NODES * 4);
    int* offs         = (int*)alloc((size_t)(N_NODES + 1) * 4);
    int* srclist      = (int*)alloc((size_t)NE * 4);

    hipMemsetAsync(deg, 0, (size_t)N_NODES * 4, stream);
    hipMemsetAsync(cursor, 0, (size_t)N_NODES * 4, stream);
    k_prep<<<1, 128, 0, stream>>>(W, a_src, a_dst, vv);
    k_gemm<<<(NSTRIP + 3) / 4, 256, 0, stream>>>(x, W, vv, h, sv);
    k_deg<<<(NE + 255) / 256, 256, 0, stream>>>(ei, deg);
    k_scan<<<1, 1024, 0, stream>>>(deg, offs);
    k_scatter<<<(NE + 255) / 256, 256, 0, stream>>>(ei, offs, cursor, srclist);
    k_aggregate<<<(N_NODES + 3) / 4, 256, 0, stream>>>(h, sv, offs, srclist, out);
}

// Round 3
// 363.457 us; speedup vs baseline: 1.1613x; 1.1613x over previous
//
#include <hip/hip_runtime.h>
#include <hip/hip_bf16.h>
#include <stdint.h>

#define N_NODES 100000
#define HEADS 4
#define NE 1600000
#define NEG_SLOPE 0.2f
#define NSTRIP 6250   /* N_NODES/16 */

typedef __attribute__((ext_vector_type(8))) short bf16x8;
typedef __attribute__((ext_vector_type(4))) float f32x4;
typedef __attribute__((ext_vector_type(2))) float f32x2;

__device__ __forceinline__ short f2bf(float f) {
    __hip_bfloat16 b = __float2bfloat16(f);
    short s; __builtin_memcpy(&s, &b, 2); return s;
}

// ---------------- K0: vv[k][0..3]=W·a_src (per head), vv[k][4..7]=W·a_dst ----------
__global__ __launch_bounds__(128) void k_prep(const float* __restrict__ W,
                                              const float* __restrict__ a_src,
                                              const float* __restrict__ a_dst,
                                              float* __restrict__ vv) {
    int k = threadIdx.x;              // 0..127
    const float* wrow = W + k * 128;
    #pragma unroll
    for (int hd = 0; hd < 4; ++hd) {
        float va = 0.f, vd = 0.f;
        #pragma unroll
        for (int d = 0; d < 32; ++d) {
            float w = wrow[hd * 32 + d];
            va += w * a_src[hd * 32 + d];
            vd += w * a_dst[hd * 32 + d];
        }
        vv[k * 8 + hd]     = va;
        vv[k * 8 + 4 + hd] = vd;
    }
}

// ---------------- K1: h=bf16(x@W) via MFMA + exact fp32 scores sv = x@vv ------------
__global__ __launch_bounds__(256) void k_gemm(const float* __restrict__ x,
                                              const float* __restrict__ W,
                                              const float* __restrict__ vv,
                                              __hip_bfloat16* __restrict__ h,
                                              float* __restrict__ sv) {
    __shared__ short wt[16384];   // swizzled Wt bf16 (32KB); reused for h transpose
    __shared__ float vvl[1024];
    const int t = threadIdx.x;

    // stage W (fp32) -> bf16 transposed + XOR swizzled
    #pragma unroll 4
    for (int i = 0; i < 64; ++i) {
        int idx = t + i * 256;                 // 16384 elems of W
        int k = idx >> 7, c = idx & 127;
        int byte = ((c << 8) + (k << 1)) ^ ((c & 7) << 4);
        *(short*)((char*)wt + byte) = f2bf(W[idx]);
    }
    *(f32x4*)(vvl + t * 4) = *(const f32x4*)(vv + t * 4);
    __syncthreads();

    const int wid = t >> 6, lane = t & 63;
    const int strip = blockIdx.x * 4 + wid;
    const bool active = strip < NSTRIP;
    const int r0 = strip * 16;
    const int lr = lane & 15, lg = lane >> 4;

    f32x4 acc[8];
    #pragma unroll
    for (int ct = 0; ct < 8; ++ct) acc[ct] = (f32x4){0.f, 0.f, 0.f, 0.f};
    float part[8];
    #pragma unroll
    for (int i = 0; i < 8; ++i) part[i] = 0.f;

    if (active) {
        bf16x8 a[4];
        #pragma unroll
        for (int kk = 0; kk < 4; ++kk) {
            const float* xp = x + (size_t)(r0 + lr) * 128 + kk * 32 + lg * 8;
            f32x4 x0 = *(const f32x4*)xp;
            f32x4 x1 = *(const f32x4*)(xp + 4);
            int kbase = kk * 32 + lg * 8;
            #pragma unroll
            for (int j = 0; j < 4; ++j) {
                a[kk][j]     = f2bf(x0[j]);
                a[kk][4 + j] = f2bf(x1[j]);
                f32x4 v0 = *(const f32x4*)(vvl + (kbase + j) * 8);
                f32x4 v1 = *(const f32x4*)(vvl + (kbase + j) * 8 + 4);
                f32x4 w0 = *(const f32x4*)(vvl + (kbase + 4 + j) * 8);
                f32x4 w1 = *(const f32x4*)(vvl + (kbase + 4 + j) * 8 + 4);
                #pragma unroll
                for (int i = 0; i < 4; ++i) {
                    part[i]     += x0[j] * v0[i] + x1[j] * w0[i];
                    part[4 + i] += x0[j] * v1[i] + x1[j] * w1[i];
                }
            }
        }
        #pragma unroll
        for (int ct = 0; ct < 8; ++ct) {
            int c = ct * 16 + lr;
            #pragma unroll
            for (int kk = 0; kk < 4; ++kk) {
                int byte = ((c << 8) + ((kk * 32 + lg * 8) << 1)) ^ ((c & 7) << 4);
                bf16x8 b = *(const bf16x8*)((char*)wt + byte);
                acc[ct] = __builtin_amdgcn_mfma_f32_16x16x32_bf16(a[kk], b, acc[ct], 0, 0, 0);
            }
        }
    }
    // butterfly-reduce score partials across the 4 lane-groups sharing a row
    #pragma unroll
    for (int i = 0; i < 8; ++i) {
        part[i] += __shfl_xor(part[i], 16);
        part[i] += __shfl_xor(part[i], 32);
    }
    if (active && lg == 0) {
        f32x4 s0, s1;
        #pragma unroll
        for (int j = 0; j < 4; ++j) { s0[j] = part[j]; s1[j] = part[4 + j]; }
        *(f32x4*)(sv + (size_t)(r0 + lr) * 8)     = s0;
        *(f32x4*)(sv + (size_t)(r0 + lr) * 8 + 4) = s1;
    }
    __syncthreads();
    // write h tile (bf16) into LDS [64 rows][128 ch], then coalesced store
    if (active) {
        #pragma unroll
        for (int ct = 0; ct < 8; ++ct) {
            #pragma unroll
            for (int j = 0; j < 4; ++j) {
                int row = wid * 16 + lg * 4 + j;
                wt[row * 128 + ct * 16 + lr] = f2bf(acc[ct][j]);
            }
        }
    }
    __syncthreads();
    const int R0 = blockIdx.x * 64;
    #pragma unroll
    for (int cch = 0; cch < 4; ++cch) {
        int sidx = (cch * 256 + t) * 8;        // short index into 16384
        int grow = R0 + (sidx >> 7);
        if (grow < N_NODES)
            *(bf16x8*)((short*)h + (size_t)grow * 128 + (sidx & 127)) = *(const bf16x8*)(wt + sidx);
    }
}

// ---------------- K3: degree histogram (4 edges/thread) -----------------------------
__global__ __launch_bounds__(256) void k_deg(const int* __restrict__ ei, int* __restrict__ deg) {
    int e4 = blockIdx.x * 256 + threadIdx.x;
    if (e4 >= NE / 4) return;
    int4 d4 = *(const int4*)(ei + NE + e4 * 4);
    atomicAdd(&deg[d4.x], 1);
    atomicAdd(&deg[d4.y], 1);
    atomicAdd(&deg[d4.z], 1);
    atomicAdd(&deg[d4.w], 1);
}

// ---------------- K4a: per-block (1024) partial sums --------------------------------
__global__ __launch_bounds__(1024) void k_scan_a(const int* __restrict__ deg, int* __restrict__ bsum) {
    __shared__ int wsum[16];
    int idx = blockIdx.x * 1024 + threadIdx.x;
    int v = (idx < N_NODES) ? deg[idx] : 0;
    #pragma unroll
    for (int off = 1; off < 64; off <<= 1) v += __shfl_xor(v, off);
    int lane = threadIdx.x & 63, wid = threadIdx.x >> 6;
    if (lane == 0) wsum[wid] = v;
    __syncthreads();
    if (threadIdx.x == 0) {
        int s = 0;
        #pragma unroll
        for (int w = 0; w < 16; ++w) s += wsum[w];
        bsum[blockIdx.x] = s;
    }
}

// ---------------- K4b: exclusive scan of 98 block sums ------------------------------
__global__ __launch_bounds__(128) void k_scan_b(const int* __restrict__ bsum, int* __restrict__ boff) {
    __shared__ int w0tot;
    int t = threadIdx.x;
    int v = (t < 98) ? bsum[t] : 0;
    int incl = v;
    #pragma unroll
    for (int off = 1; off < 64; off <<= 1) {
        int y = __shfl_up(incl, off);
        if ((t & 63) >= off) incl += y;
    }
    if (t == 63) w0tot = incl;
    __syncthreads();
    int excl = incl - v + ((t >= 64) ? w0tot : 0);
    if (t < 98) boff[t] = excl;
}

// ---------------- K4c: local rescan + add block offset -> offs, cursor --------------
__global__ __launch_bounds__(1024) void k_scan_c(const int* __restrict__ deg,
                                                 const int* __restrict__ boff,
                                                 int* __restrict__ offs,
                                                 int* __restrict__ cursor) {
    __shared__ int wsum[16];
    int t = threadIdx.x;
    int idx = blockIdx.x * 1024 + t;
    int lane = t & 63, wid = t >> 6;
    int v = (idx < N_NODES) ? deg[idx] : 0;
    int incl = v;
    #pragma unroll
    for (int off = 1; off < 64; off <<= 1) {
        int y = __shfl_up(incl, off);
        if (lane >= off) incl += y;
    }
    if (lane == 63) wsum[wid] = incl;
    __syncthreads();
    int pre = 0;
    #pragma unroll
    for (int w = 0; w < 16; ++w)
        if (w < wid) pre += wsum[w];
    int excl = boff[blockIdx.x] + pre + incl - v;
    if (idx < N_NODES) { offs[idx] = excl; cursor[idx] = excl; }
    if (idx == 0) offs[N_NODES] = NE;
}

// ---------------- K5: scatter edges into CSR buckets (4 edges/thread) ---------------
__global__ __launch_bounds__(256) void k_scatter(const int* __restrict__ ei,
                                                 int* __restrict__ cursor,
                                                 int* __restrict__ srclist) {
    int e4 = blockIdx.x * 256 + threadIdx.x;
    if (e4 >= NE / 4) return;
    int4 s4 = *(const int4*)(ei + e4 * 4);
    int4 d4 = *(const int4*)(ei + NE + e4 * 4);
    int p0 = atomicAdd(&cursor[d4.x], 1); srclist[p0] = s4.x;
    int p1 = atomicAdd(&cursor[d4.y], 1); srclist[p1] = s4.y;
    int p2 = atomicAdd(&cursor[d4.z], 1); srclist[p2] = s4.z;
    int p3 = atomicAdd(&cursor[d4.w], 1); srclist[p3] = s4.w;
}

// ---------------- K6: per-dst aggregate (one wave per node, 8-wide MLP) --------------
__global__ __launch_bounds__(256) void k_aggregate(const __hip_bfloat16* __restrict__ h,
                                                   const float* __restrict__ sv,
                                                   const int* __restrict__ offs,
                                                   const int* __restrict__ srclist,
                                                   float* __restrict__ out) {
    int gw = (blockIdx.x * 256 + threadIdx.x) >> 6;
    if (gw >= N_NODES) return;
    int n = gw;
    int lane = threadIdx.x & 63;
    int head = lane >> 4;             // channels 2*lane,2*lane+1 belong to head lane>>4
    float sd = sv[(size_t)n * 8 + 4 + head];
    int b = offs[n], e = offs[n + 1];
    float acc0 = 0.f, acc1 = 0.f, wsum = 0.f;
    const uint32_t* hp = (const uint32_t*)h;
    for (int j = b; j < e; j += 8) {
        int s[8];
        uint32_t p[8];
        float w[8];
        #pragma unroll
        for (int u = 0; u < 8; ++u) {
            int jj = j + u;
            s[u] = srclist[jj < e ? jj : e - 1];
        }
        #pragma unroll
        for (int u = 0; u < 8; ++u) p[u] = hp[(size_t)s[u] * 64 + lane];
        #pragma unroll
        for (int u = 0; u < 8; ++u) {
            float ew = sv[(size_t)s[u] * 8 + head] + sd;
            ew = ew > 0.f ? ew : NEG_SLOPE * ew;
            w[u] = (j + u < e) ? __expf(ew) : 0.f;
        }
        #pragma unroll
        for (int u = 0; u < 8; ++u) {
            union { uint32_t i; float f; } u0, u1;
            u0.i = p[u] << 16;
            u1.i = p[u] & 0xffff0000u;
            acc0 += w[u] * u0.f;
            acc1 += w[u] * u1.f;
            wsum += w[u];
        }
    }
    float inv = 1.f / (wsum + 1e-9f);
    f32x2 o = {acc0 * inv, acc1 * inv};
    *(f32x2*)(out + (size_t)n * 128 + lane * 2) = o;
}

extern "C" void kernel_launch(void* const* d_in, const int* in_sizes, int n_in,
                              void* d_out, int out_size, void* d_ws, size_t ws_size,
                              hipStream_t stream) {
    const float* x     = (const float*)d_in[0];
    const int*   ei    = (const int*)d_in[1];
    const float* W     = (const float*)d_in[2];
    const float* a_src = (const float*)d_in[3];
    const float* a_dst = (const float*)d_in[4];
    float* out = (float*)d_out;

    char* ws = (char*)d_ws;
    size_t off = 0;
    auto alloc = [&](size_t bytes) {
        char* p = ws + off;
        off += (bytes + 255) & ~(size_t)255;
        return p;
    };
    __hip_bfloat16* h = (__hip_bfloat16*)alloc((size_t)N_NODES * 128 * 2);
    float* sv         = (float*)alloc((size_t)N_NODES * 8 * 4);
    float* vv         = (float*)alloc(1024 * 4);
    int* deg          = (int*)alloc((size_t)N_NODES * 4);
    int* cursor       = (int*)alloc((size_t)N_NODES * 4);
    int* offs         = (int*)alloc((size_t)(N_NODES + 1) * 4);
    int* srclist      = (int*)alloc((size_t)NE * 4);
    int* bsum         = (int*)alloc(128 * 4);
    int* boff         = (int*)alloc(128 * 4);

    hipMemsetAsync(deg, 0, (size_t)N_NODES * 4, stream);
    k_prep<<<1, 128, 0, stream>>>(W, a_src, a_dst, vv);
    k_gemm<<<(NSTRIP + 3) / 4, 256, 0, stream>>>(x, W, vv, h, sv);
    k_deg<<<(NE / 4 + 255) / 256, 256, 0, stream>>>(ei, deg);
    k_scan_a<<<98, 1024, 0, stream>>>(deg, bsum);
    k_scan_b<<<1, 128, 0, stream>>>(bsum, boff);
    k_scan_c<<<98, 1024, 0, stream>>>(deg, boff, offs, cursor);
    k_scatter<<<(NE / 4 + 255) / 256, 256, 0, stream>>>(ei, cursor, srclist);
    k_aggregate<<<(N_NODES + 3) / 4, 256, 0, stream>>>(h, sv, offs, srclist, out);
}